// Round 1
// 253.553 us; speedup vs baseline: 1.0204x; 1.0204x over previous
//
#include <hip/hip_runtime.h>
#include <hip/hip_bf16.h>

// B=8, LQ=LK=2048, D=128, fp32 in/out, softmax(qk*scale) @ V.
// Strategy: bf16x3 split-precision QK^T (fp32-accurate logits), fp32 online
// softmax, bf16 PV. K-split=2 + merge for occupancy (512 blocks, 2/CU).
// R1: software-pipeline the k-loop one iteration deep (T14 async-stage split):
//     prefetch next K/V tile + next scale sub-tile into registers during the
//     current iteration's QK/softmax/PV, hiding the ~900-cycle global latency
//     that previously stalled every iteration (latency-bound: all pipes <20%).

typedef float          f32x4 __attribute__((ext_vector_type(4)));
typedef short          s16x8 __attribute__((ext_vector_type(8)));
typedef unsigned int   u32x4 __attribute__((ext_vector_type(4)));
typedef unsigned short u16x4 __attribute__((ext_vector_type(4)));

#define LOG2E 1.4426950408889634f

__device__ __forceinline__ float fast_exp2(float x) {
#if __has_builtin(__builtin_amdgcn_exp2f)
    return __builtin_amdgcn_exp2f(x);
#else
    return exp2f(x);
#endif
}

__device__ __forceinline__ unsigned short f2bf(float x) {
    return __builtin_bit_cast(unsigned short, __float2bfloat16(x));
}
__device__ __forceinline__ float bf2f(unsigned short u) {
    return __bfloat162float(__builtin_bit_cast(__hip_bfloat16, u));
}

// ---------------- fp32 -> bf16 hi/lo split (Q and K) ----------------
__global__ void conv_split(const float* __restrict__ src,
                           unsigned short* __restrict__ hi,
                           unsigned short* __restrict__ lo, int n4) {
    int i = blockIdx.x * blockDim.x + threadIdx.x;
    if (i >= n4) return;
    const float4 v = ((const float4*)src)[i];
    float f[4] = {v.x, v.y, v.z, v.w};
    u16x4 h, l;
#pragma unroll
    for (int j = 0; j < 4; ++j) {
        unsigned short hb = f2bf(f[j]);
        h[j] = hb;
        l[j] = f2bf(f[j] - bf2f(hb));
    }
    ((u16x4*)hi)[i] = h;
    ((u16x4*)lo)[i] = l;
}

// ---------------- V [b][k][d] fp32 -> V^T [b][d][k] bf16 ----------------
__global__ void transpose_v(const float* __restrict__ v,
                            unsigned short* __restrict__ vt) {
    __shared__ unsigned short tile[64 * 132];   // [k][d], stride 132 breaks conflicts
    const int b   = blockIdx.x & 7;
    const int k0  = (blockIdx.x >> 3) * 64;
    const int tid = threadIdx.x;
#pragma unroll
    for (int p = 0; p < 8; ++p) {
        int idx  = p * 256 + tid;     // 0..2047
        int k    = idx >> 5;          // 0..63
        int dblk = idx & 31;          // d = dblk*4
        float4 val = ((const float4*)v)[((b * 2048 + k0 + k) * 128 + dblk * 4) >> 2];
        u16x4 t4;
        t4[0] = f2bf(val.x); t4[1] = f2bf(val.y);
        t4[2] = f2bf(val.z); t4[3] = f2bf(val.w);
        *(u16x4*)&tile[k * 132 + dblk * 4] = t4;
    }
    __syncthreads();
#pragma unroll
    for (int p = 0; p < 4; ++p) {
        int idx = p * 256 + tid;      // 0..1023
        int d   = idx >> 3;           // 0..127
        int k8  = idx & 7;            // 0..7
        u16x4 a, c;
#pragma unroll
        for (int j = 0; j < 4; ++j) a[j] = tile[(k8 * 8 + j) * 132 + d];
#pragma unroll
        for (int j = 0; j < 4; ++j) c[j] = tile[(k8 * 8 + 4 + j) * 132 + d];
        unsigned short* outp = vt + (b * 128 + d) * 2048 + k0 + k8 * 8;
        *(u16x4*)outp       = a;
        *(u16x4*)(outp + 4) = c;
    }
}

// ---------------- flash attention main kernel ----------------
#define KHS 136   // K-tile LDS row stride (64 rows x 128 d, +8 pad)
#define VTS 72    // V^T LDS row stride (128 rows x 64 k, +8 pad)
#define PS  72    // P LDS row stride

__global__ __launch_bounds__(256, 2)
void flash_fwd(const unsigned short* __restrict__ qh_g,
               const unsigned short* __restrict__ ql_g,
               const unsigned short* __restrict__ kh_g,
               const unsigned short* __restrict__ kl_g,
               const unsigned short* __restrict__ vt_g,
               const float* __restrict__ scale_g,
               float* __restrict__ opart,
               float* __restrict__ mpart,
               float* __restrict__ lpart) {
    __shared__ unsigned short lds_kh[64 * KHS];
    __shared__ unsigned short lds_kl[64 * KHS];
    __shared__ unsigned short lds_vt[128 * VTS];
    __shared__ unsigned short lds_p[4][16 * PS];   // per-wave private

    const int tid  = threadIdx.x;
    const int wave = tid >> 6;
    const int lane = tid & 63;
    const int c    = lane & 15;   // MFMA n / m index
    const int g    = lane >> 4;   // quad

    const int bid   = blockIdx.x;
    const int b     = bid & 7;            // batch <-> XCD affinity
    const int qt    = (bid >> 3) & 31;
    const int ks    = bid >> 8;           // k-split half: 0/1
    const int q0    = qt * 64;
    const int kbase = ks * 1024;

    // staging thread mapping (global->reg->LDS)
    const int srow = tid >> 4, sc8 = tid & 15;   // K tiles
    const int sdv  = tid >> 3, sk8 = tid & 7;    // V^T tile

    // Q fragments (A layout: m=lane&15 -> q row, k=quad*8+j -> d)
    s16x8 qh[4], ql[4];
    {
        const int qrow = b * 2048 + q0 + wave * 16 + c;
#pragma unroll
        for (int kstep = 0; kstep < 4; ++kstep) {
            int idx = qrow * 16 + kstep * 4 + g;
            qh[kstep] = __builtin_bit_cast(s16x8, ((const u32x4*)qh_g)[idx]);
            ql[kstep] = __builtin_bit_cast(s16x8, ((const u32x4*)ql_g)[idx]);
        }
    }

    f32x4 oacc[8];
#pragma unroll
    for (int t = 0; t < 8; ++t) oacc[t] = (f32x4){0.f, 0.f, 0.f, 0.f};
    float m2[4], ln[4];
#pragma unroll
    for (int r = 0; r < 4; ++r) { m2[r] = -INFINITY; ln[r] = 0.f; }

    // ---- prefetch state (one iteration deep) ----
    u32x4 pk[4], pl[4], pv[4];   // next K_hi / K_lo / V^T tile
    float scn[4][4];             // next scale sub-tile
    const int scb = (b * 2048 + q0 + wave * 16 + g * 4) * 2048 + c;

    // prologue: issue tile 0 + scale 0
    {
        const int k0 = kbase;
#pragma unroll
        for (int p = 0; p < 4; ++p) {
            int gidx = (b * 2048 + k0 + p * 16 + srow) * 16 + sc8;
            pk[p] = ((const u32x4*)kh_g)[gidx];
            pl[p] = ((const u32x4*)kl_g)[gidx];
            int vidx = (b * 128 + p * 32 + sdv) * 256 + (k0 >> 3) + sk8;
            pv[p] = ((const u32x4*)vt_g)[vidx];
        }
#pragma unroll
        for (int t = 0; t < 4; ++t)
#pragma unroll
            for (int r = 0; r < 4; ++r)
                scn[t][r] = scale_g[scb + r * 2048 + k0 + t * 16];
    }

    for (int kc = 0; kc < 16; ++kc) {
        const int k0 = kbase + kc * 64;

        // ---- commit prefetched K_hi, K_lo, V^T to LDS ----
        __syncthreads();
#pragma unroll
        for (int p = 0; p < 4; ++p) {
            *(u32x4*)&lds_kh[(p * 16 + srow) * KHS + sc8 * 8] = pk[p];
            *(u32x4*)&lds_kl[(p * 16 + srow) * KHS + sc8 * 8] = pl[p];
            *(u32x4*)&lds_vt[(p * 32 + sdv) * VTS + sk8 * 8]  = pv[p];
        }
        __syncthreads();

        // ---- consume prefetched scale (pre-multiplied by log2e) ----
        float sc[4][4];
#pragma unroll
        for (int t = 0; t < 4; ++t)
#pragma unroll
            for (int r = 0; r < 4; ++r)
                sc[t][r] = scn[t][r] * LOG2E;

        // ---- issue next iteration's tile + scale loads (overlap compute) ----
        if (kc < 15) {
            const int kn = k0 + 64;
#pragma unroll
            for (int p = 0; p < 4; ++p) {
                int gidx = (b * 2048 + kn + p * 16 + srow) * 16 + sc8;
                pk[p] = ((const u32x4*)kh_g)[gidx];
                pl[p] = ((const u32x4*)kl_g)[gidx];
                int vidx = (b * 128 + p * 32 + sdv) * 256 + (kn >> 3) + sk8;
                pv[p] = ((const u32x4*)vt_g)[vidx];
            }
#pragma unroll
            for (int t = 0; t < 4; ++t)
#pragma unroll
                for (int r = 0; r < 4; ++r)
                    scn[t][r] = scale_g[scb + r * 2048 + kn + t * 16];
        }

        // ---- S = Q K^T, bf16x3 split for ~fp32 accuracy ----
        f32x4 s[4];
#pragma unroll
        for (int t = 0; t < 4; ++t) s[t] = (f32x4){0.f, 0.f, 0.f, 0.f};
#pragma unroll
        for (int kstep = 0; kstep < 4; ++kstep) {
#pragma unroll
            for (int t = 0; t < 4; ++t) {
                int off = (t * 16 + c) * KHS + kstep * 32 + g * 8;
                s16x8 bh = *(const s16x8*)&lds_kh[off];
                s16x8 bl = *(const s16x8*)&lds_kl[off];
                s[t] = __builtin_amdgcn_mfma_f32_16x16x32_bf16(qh[kstep], bh, s[t], 0, 0, 0);
                s[t] = __builtin_amdgcn_mfma_f32_16x16x32_bf16(ql[kstep], bh, s[t], 0, 0, 0);
                s[t] = __builtin_amdgcn_mfma_f32_16x16x32_bf16(qh[kstep], bl, s[t], 0, 0, 0);
            }
        }

        // ---- online softmax (rows live in 16-lane groups; 4 rows/lane) ----
        float lt[4][4], mx[4];
#pragma unroll
        for (int r = 0; r < 4; ++r) {
            lt[0][r] = s[0][r] * sc[0][r];
            lt[1][r] = s[1][r] * sc[1][r];
            lt[2][r] = s[2][r] * sc[2][r];
            lt[3][r] = s[3][r] * sc[3][r];
            mx[r] = fmaxf(fmaxf(lt[0][r], lt[1][r]), fmaxf(lt[2][r], lt[3][r]));
        }
#pragma unroll
        for (int mask = 1; mask < 16; mask <<= 1)
#pragma unroll
            for (int r = 0; r < 4; ++r)
                mx[r] = fmaxf(mx[r], __shfl_xor(mx[r], mask));
        float al[4], rs[4];
#pragma unroll
        for (int r = 0; r < 4; ++r) {
            float mn = fmaxf(m2[r], mx[r]);
            al[r] = fast_exp2(m2[r] - mn);   // first iter: exp2(-inf)=0
            m2[r] = mn;
            rs[r] = 0.f;
        }
#pragma unroll
        for (int t = 0; t < 4; ++t)
#pragma unroll
            for (int r = 0; r < 4; ++r) {
                float p = fast_exp2(lt[t][r] - m2[r]);
                rs[r] += p;
                lds_p[wave][(g * 4 + r) * PS + t * 16 + c] = f2bf(p);
            }
#pragma unroll
        for (int mask = 1; mask < 16; mask <<= 1)
#pragma unroll
            for (int r = 0; r < 4; ++r)
                rs[r] += __shfl_xor(rs[r], mask);
#pragma unroll
        for (int r = 0; r < 4; ++r) ln[r] = ln[r] * al[r] + rs[r];
#pragma unroll
        for (int t = 0; t < 8; ++t)
#pragma unroll
            for (int r = 0; r < 4; ++r) oacc[t][r] *= al[r];

        // ---- O += P V (P via per-wave LDS round-trip C->A layout) ----
#pragma unroll
        for (int k2 = 0; k2 < 2; ++k2) {
            s16x8 af = *(const s16x8*)&lds_p[wave][c * PS + k2 * 32 + g * 8];
#pragma unroll
            for (int t2 = 0; t2 < 8; ++t2) {
                s16x8 bv = *(const s16x8*)&lds_vt[(t2 * 16 + c) * VTS + k2 * 32 + g * 8];
                oacc[t2] = __builtin_amdgcn_mfma_f32_16x16x32_bf16(af, bv, oacc[t2], 0, 0, 0);
            }
        }
    }

    // ---- write unnormalized partials + stats ----
    {
        const int rowb = (ks * 8 + b) * 2048 + q0 + wave * 16;
#pragma unroll
        for (int t2 = 0; t2 < 8; ++t2)
#pragma unroll
            for (int r = 0; r < 4; ++r)
                opart[(rowb + g * 4 + r) * 128 + t2 * 16 + c] = oacc[t2][r];
        if (c == 0) {
#pragma unroll
            for (int r = 0; r < 4; ++r) {
                mpart[rowb + g * 4 + r] = m2[r];
                lpart[rowb + g * 4 + r] = ln[r];
            }
        }
    }
}

// ---------------- merge the two k-split halves ----------------
__global__ void merge_halves(const float* __restrict__ opart,
                             const float* __restrict__ mpart,
                             const float* __restrict__ lpart,
                             float* __restrict__ out) {
    const int row = blockIdx.x;     // b*2048 + q
    const int d   = threadIdx.x;    // 0..127
    const float m0 = mpart[row],  m1 = mpart[16384 + row];
    const float l0 = lpart[row],  l1 = lpart[16384 + row];
    const float M  = fmaxf(m0, m1);
    const float a0 = fast_exp2(m0 - M);
    const float a1 = fast_exp2(m1 - M);
    const float inv = 1.f / (a0 * l0 + a1 * l1);
    const int i = row * 128 + d;
    out[i] = (a0 * opart[i] + a1 * opart[16384 * 128 + i]) * inv;
}

extern "C" void kernel_launch(void* const* d_in, const int* in_sizes, int n_in,
                              void* d_out, int out_size, void* d_ws, size_t ws_size,
                              hipStream_t stream) {
    const float* q  = (const float*)d_in[0];
    const float* k  = (const float*)d_in[1];
    const float* v  = (const float*)d_in[2];
    const float* sc = (const float*)d_in[3];
    float* out = (float*)d_out;

    char* ws = (char*)d_ws;
    const size_t MB = 1024 * 1024;
    unsigned short* qh = (unsigned short*)(ws);
    unsigned short* ql = (unsigned short*)(ws + 4 * MB);
    unsigned short* kh = (unsigned short*)(ws + 8 * MB);
    unsigned short* kl = (unsigned short*)(ws + 12 * MB);
    unsigned short* vt = (unsigned short*)(ws + 16 * MB);
    float* opart = (float*)(ws + 20 * MB);                 // [2][8*2048][128]
    float* mpart = (float*)(ws + 36 * MB);                 // [2][16384]
    float* lpart = (float*)(ws + 36 * MB + 128 * 1024);    // [2][16384]

    conv_split<<<2048, 256, 0, stream>>>(q, qh, ql, 524288);
    conv_split<<<2048, 256, 0, stream>>>(k, kh, kl, 524288);
    transpose_v<<<256, 256, 0, stream>>>(v, vt);
    flash_fwd<<<512, 256, 0, stream>>>(qh, ql, kh, kl, vt, sc, opart, mpart, lpart);
    merge_halves<<<16384, 128, 0, stream>>>(opart, mpart, lpart, out);
}